// Round 7
// baseline (544.417 us; speedup 1.0000x reference)
//
#include <hip/hip_runtime.h>

#define N_ATOMS   100000
#define N_BONDS   200000
#define MAX_NB    6
#define AF        39
#define BFEAT     50      // 39 + 11
#define H         128
#define DEPTH     6
#define KS_I      2       // k-steps (32 each) for the three GEMMs
#define KS_H      4
#define KS_O      6

typedef unsigned short ushort_t;
typedef unsigned int   uint_t;

typedef __attribute__((ext_vector_type(8))) short  bf16x8;
typedef __attribute__((ext_vector_type(4))) float  f32x4;

__device__ inline float bf2f(ushort_t u) {
    union { uint_t i; float f; } v; v.i = ((uint_t)u) << 16; return v.f;
}
__device__ inline ushort_t f2bf(float f) {
    union { float f; uint_t i; } v; v.f = f;
    uint_t x = v.i;
    uint_t r = (x + 0x7fffu + ((x >> 16) & 1u)) >> 16;   // RNE
    return (ushort_t)r;
}
__device__ inline uint_t pack2(float a, float b) {
    return (uint_t)f2bf(a) | ((uint_t)f2bf(b) << 16);
}
__device__ inline uint_t relu2(uint_t w) {
    uint_t lo = w & 0xffffu, hi = w >> 16;
    if (lo & 0x8000u) lo = 0;
    if (hi & 0x8000u) hi = 0;
    return lo | (hi << 16);
}
__device__ inline void addv(float* a, uint4 v) {
    a[0] += bf2f((ushort_t)(v.x & 0xffffu)); a[1] += bf2f((ushort_t)(v.x >> 16));
    a[2] += bf2f((ushort_t)(v.y & 0xffffu)); a[3] += bf2f((ushort_t)(v.y >> 16));
    a[4] += bf2f((ushort_t)(v.z & 0xffffu)); a[5] += bf2f((ushort_t)(v.z >> 16));
    a[6] += bf2f((ushort_t)(v.w & 0xffffu)); a[7] += bf2f((ushort_t)(v.w >> 16));
}
__device__ inline bf16x8 pack8(const float* a) {
    union { uint4 u; bf16x8 h; } c;
    c.u.x = pack2(a[0], a[1]); c.u.y = pack2(a[2], a[3]);
    c.u.z = pack2(a[4], a[5]); c.u.w = pack2(a[6], a[7]);
    return c.h;
}

// ---------------------------------------------------------------------------
// Prep: pack W_i / W_h / W_o into MFMA B-fragment-major bf16 layout:
//   p[ks][nt][lane][j]  with  n = nt*16 + (lane&15),  k = ks*32 + (lane>>4)*8 + j
// ---------------------------------------------------------------------------
__global__ __launch_bounds__(256) void k_pack(const float* __restrict__ W_i,
                                              const float* __restrict__ W_h,
                                              const float* __restrict__ W_o,
                                              ushort_t* __restrict__ pWi,
                                              ushort_t* __restrict__ pWh,
                                              ushort_t* __restrict__ pWo) {
    int id = blockIdx.x * 256 + threadIdx.x;
    int mat;
    ushort_t* dst;
    if (id < 1024)        { mat = 0; dst = pWi; }
    else if (id < 3072)   { mat = 1; dst = pWh; id -= 1024; }
    else                  { mat = 2; dst = pWo; id -= 3072; }
    const int lane = id & 63;
    const int nt   = (id >> 6) & 7;
    const int ks   = id >> 9;
    const int n  = nt * 16 + (lane & 15);
    const int k0 = ks * 32 + (lane >> 4) * 8;
    float v[8];
#pragma unroll
    for (int j = 0; j < 8; ++j) {
        const int k = k0 + j;
        float x = 0.f;
        if (mat == 0)      { if (k < BFEAT) x = W_i[n * BFEAT + k]; }
        else if (mat == 1) { x = W_h[n * H + k]; }
        else {
            if (k < H)          x = W_o[(size_t)n * (AF + H) + AF + k];
            else if (k < H + AF) x = W_o[(size_t)n * (AF + H) + (k - H)];
        }
        v[j] = x;
    }
    uint4 u;
    u.x = pack2(v[0], v[1]); u.y = pack2(v[2], v[3]);
    u.z = pack2(v[4], v[5]); u.w = pack2(v[6], v[7]);
    ((uint4*)dst)[id] = u;
}

// ---------------------------------------------------------------------------
// Kernel 1: binput = fbonds @ W_i^T (bf16); msg = relu(binput) (bf16)
// (unchanged from R6 — not the bottleneck)
// ---------------------------------------------------------------------------
__global__ __launch_bounds__(256) void k_binput(const float* __restrict__ fbonds,
                                                const ushort_t* __restrict__ pWi,
                                                ushort_t* __restrict__ binput,
                                                ushort_t* __restrict__ msg) {
    __shared__ __align__(16) ushort_t sAC[64][136];   // 17408 B
    const int t = threadIdx.x;
    const int b0 = blockIdx.x * 64;

    for (int i = t; i < 64 * 64; i += 256) {
        const int row = i >> 6, k = i & 63;
        sAC[row][k] = (k < BFEAT) ? f2bf(fbonds[(size_t)(b0 + row) * BFEAT + k]) : (ushort_t)0;
    }
    __syncthreads();

    const int w    = t >> 6;
    const int lane = t & 63;
    const int col  = lane & 15;
    const int kg   = lane >> 4;
    const int m    = 16 * w + col;

    f32x4 acc[8];
#pragma unroll
    for (int nt = 0; nt < 8; ++nt) acc[nt] = (f32x4){0.f, 0.f, 0.f, 0.f};
    bf16x8 af[KS_I];
#pragma unroll
    for (int ks = 0; ks < KS_I; ++ks)
        af[ks] = *(const bf16x8*)&sAC[m][ks * 32 + kg * 8];
#pragma unroll
    for (int ks = 0; ks < KS_I; ++ks) {
#pragma unroll
        for (int nt = 0; nt < 8; ++nt) {
            const bf16x8 b = *(const bf16x8*)(pWi + (((size_t)(ks * 8 + nt) * 64 + lane) * 8));
            acc[nt] = __builtin_amdgcn_mfma_f32_16x16x32_bf16(af[ks], b, acc[nt], 0, 0, 0);
        }
    }
    const int row0 = kg * 4;
#pragma unroll
    for (int nt = 0; nt < 8; ++nt)
#pragma unroll
        for (int r = 0; r < 4; ++r)
            sAC[16 * w + row0 + r][nt * 16 + col] = f2bf(acc[nt][r]);
    __syncthreads();

    for (int i = t; i < 64 * 16; i += 256) {
        const int row = i >> 4, c0 = (i & 15) * 8;
        const uint4 v = *(const uint4*)&sAC[row][c0];
        uint4 rl;
        rl.x = relu2(v.x); rl.y = relu2(v.y); rl.z = relu2(v.z); rl.w = relu2(v.w);
        const size_t off = (size_t)(b0 + row) * H + c0;
        *(uint4*)(binput + off) = v;
        *(uint4*)(msg + off)    = rl;
    }
}

// ---------------------------------------------------------------------------
// Fused MP step — WAVE-INDEPENDENT, ZERO __syncthreads.
// Wave w owns rows b0+16w..+15. Lane l (r=l&15, cg=l>>4):
//   gather sums for (row r, cols ks*32+cg*8..+7) land directly in af[ks].
// MFMA B-frags streamed from packed global (L2). C transposed through a
// per-wave LDS slab (intra-wave: s_waitcnt lgkmcnt(0), no barrier).
// LDS 17408 B total.
// ---------------------------------------------------------------------------
__global__ __launch_bounds__(256) void k_mp(const ushort_t* __restrict__ msg_in,
                                            const int* __restrict__ bgraph,
                                            const ushort_t* __restrict__ pWh,
                                            const ushort_t* __restrict__ binput,
                                            ushort_t* __restrict__ msg_out) {
    __shared__ __align__(16) ushort_t sC[4][16][136];   // per-wave C stage
    const int t = threadIdx.x;
    const int w    = t >> 6;
    const int lane = t & 63;
    const int r    = lane & 15;
    const int cg   = lane >> 4;                  // 0..3
    const int rowg = blockIdx.x * 64 + w * 16 + r;

    // neighbor indices for this lane's row (4-way redundant across cg; L1-cached)
    const int* ip = bgraph + (size_t)rowg * MAX_NB;
    int idx[MAX_NB];
#pragma unroll
    for (int j = 0; j < MAX_NB; ++j) idx[j] = ip[j];

    // gather-sum straight into A-fragments
    bf16x8 af[KS_H];
#pragma unroll
    for (int ks = 0; ks < KS_H; ++ks) {
        const int c0 = ks * 32 + cg * 8;
        uint4 v[MAX_NB];
#pragma unroll
        for (int j = 0; j < MAX_NB; ++j)
            v[j] = *(const uint4*)(msg_in + (size_t)idx[j] * H + c0);
        float a[8];
#pragma unroll
        for (int q = 0; q < 8; ++q) a[q] = 0.f;
#pragma unroll
        for (int j = 0; j < MAX_NB; ++j) addv(a, v[j]);
        af[ks] = pack8(a);
    }

    // MFMA: 16x128 slab per wave
    f32x4 acc[8];
#pragma unroll
    for (int nt = 0; nt < 8; ++nt) acc[nt] = (f32x4){0.f, 0.f, 0.f, 0.f};
#pragma unroll
    for (int ks = 0; ks < KS_H; ++ks) {
#pragma unroll
        for (int nt = 0; nt < 8; ++nt) {
            const bf16x8 b = *(const bf16x8*)(pWh + (((size_t)(ks * 8 + nt) * 64 + lane) * 8));
            acc[nt] = __builtin_amdgcn_mfma_f32_16x16x32_bf16(af[ks], b, acc[nt], 0, 0, 0);
        }
    }

    // C -> per-wave LDS (bf16), transpose for coalesced epilogue
#pragma unroll
    for (int nt = 0; nt < 8; ++nt)
#pragma unroll
        for (int rr = 0; rr < 4; ++rr)
            sC[w][cg * 4 + rr][nt * 16 + r] = f2bf(acc[nt][rr]);
    asm volatile("s_waitcnt lgkmcnt(0)" ::: "memory");

    // epilogue: +binput, relu, pack, store. 4 passes, 256B contiguous per 16 lanes.
    const int base = blockIdx.x * 64 + w * 16;
#pragma unroll
    for (int p = 0; p < 4; ++p) {
        const int erow = p * 4 + cg;
        const size_t off = (size_t)(base + erow) * H + r * 8;
        const uint4 cc  = *(const uint4*)&sC[w][erow][r * 8];
        const uint4 bi4 = *(const uint4*)(binput + off);
        uint4 o; float v0, v1;
        v0 = bf2f((ushort_t)(bi4.x & 0xffffu)) + bf2f((ushort_t)(cc.x & 0xffffu));
        v1 = bf2f((ushort_t)(bi4.x >> 16))     + bf2f((ushort_t)(cc.x >> 16));
        o.x = pack2(v0 > 0.f ? v0 : 0.f, v1 > 0.f ? v1 : 0.f);
        v0 = bf2f((ushort_t)(bi4.y & 0xffffu)) + bf2f((ushort_t)(cc.y & 0xffffu));
        v1 = bf2f((ushort_t)(bi4.y >> 16))     + bf2f((ushort_t)(cc.y >> 16));
        o.y = pack2(v0 > 0.f ? v0 : 0.f, v1 > 0.f ? v1 : 0.f);
        v0 = bf2f((ushort_t)(bi4.z & 0xffffu)) + bf2f((ushort_t)(cc.z & 0xffffu));
        v1 = bf2f((ushort_t)(bi4.z >> 16))     + bf2f((ushort_t)(cc.z >> 16));
        o.z = pack2(v0 > 0.f ? v0 : 0.f, v1 > 0.f ? v1 : 0.f);
        v0 = bf2f((ushort_t)(bi4.w & 0xffffu)) + bf2f((ushort_t)(cc.w & 0xffffu));
        v1 = bf2f((ushort_t)(bi4.w >> 16))     + bf2f((ushort_t)(cc.w >> 16));
        o.w = pack2(v0 > 0.f ? v0 : 0.f, v1 > 0.f ? v1 : 0.f);
        *(uint4*)(msg_out + off) = o;
    }
}

// ---------------------------------------------------------------------------
// Fused output — WAVE-INDEPENDENT, ZERO __syncthreads.
// A = [a_nei(128) | fatoms(39) | pad(25)], K = 192. ks 0..3 gather, ks 4..5
// from fatoms directly. fp32 C staging per wave (33792 B -> 4 blocks/CU).
// ---------------------------------------------------------------------------
__global__ __launch_bounds__(256) void k_out(const ushort_t* __restrict__ msg,
                                             const int* __restrict__ agraph,
                                             const float* __restrict__ fatoms,
                                             const ushort_t* __restrict__ pWo,
                                             const float* __restrict__ b_o,
                                             float* __restrict__ out) {
    __shared__ __align__(16) float sC[4][16][132];   // per-wave f32 C stage
    const int t = threadIdx.x;
    const int w    = t >> 6;
    const int lane = t & 63;
    const int r    = lane & 15;
    const int cg   = lane >> 4;
    const int rowg = blockIdx.x * 64 + w * 16 + r;
    const int rowc = rowg < N_ATOMS ? rowg : N_ATOMS - 1;   // clamp for loads

    const int* ip = agraph + (size_t)rowc * MAX_NB;
    int idx[MAX_NB];
#pragma unroll
    for (int j = 0; j < MAX_NB; ++j) idx[j] = ip[j];

    bf16x8 af[KS_O];
#pragma unroll
    for (int ks = 0; ks < 4; ++ks) {
        const int c0 = ks * 32 + cg * 8;
        uint4 v[MAX_NB];
#pragma unroll
        for (int j = 0; j < MAX_NB; ++j)
            v[j] = *(const uint4*)(msg + (size_t)idx[j] * H + c0);
        float a[8];
#pragma unroll
        for (int q = 0; q < 8; ++q) a[q] = 0.f;
#pragma unroll
        for (int j = 0; j < MAX_NB; ++j) addv(a, v[j]);
        af[ks] = pack8(a);
    }
#pragma unroll
    for (int ks = 4; ks < 6; ++ks) {
        float a[8];
#pragma unroll
        for (int q = 0; q < 8; ++q) {
            const int f = (ks - 4) * 32 + cg * 8 + q;
            a[q] = (f < AF) ? fatoms[(size_t)rowc * AF + f] : 0.f;
        }
        af[ks] = pack8(a);
    }

    f32x4 acc[8];
#pragma unroll
    for (int nt = 0; nt < 8; ++nt) acc[nt] = (f32x4){0.f, 0.f, 0.f, 0.f};
#pragma unroll
    for (int ks = 0; ks < KS_O; ++ks) {
#pragma unroll
        for (int nt = 0; nt < 8; ++nt) {
            const bf16x8 b = *(const bf16x8*)(pWo + (((size_t)(ks * 8 + nt) * 64 + lane) * 8));
            acc[nt] = __builtin_amdgcn_mfma_f32_16x16x32_bf16(af[ks], b, acc[nt], 0, 0, 0);
        }
    }

#pragma unroll
    for (int nt = 0; nt < 8; ++nt)
#pragma unroll
        for (int rr = 0; rr < 4; ++rr)
            sC[w][cg * 4 + rr][nt * 16 + r] = acc[nt][rr];
    asm volatile("s_waitcnt lgkmcnt(0)" ::: "memory");

    const int base = blockIdx.x * 64 + w * 16;
    const float4* bo4 = (const float4*)b_o;
#pragma unroll
    for (int p = 0; p < 4; ++p) {
        const int erow = p * 4 + cg;
        const int a = base + erow;
        if (a < N_ATOMS) {
            const float* cp = &sC[w][erow][r * 8];
            const float4 b1 = bo4[r * 2];
            const float4 b2 = bo4[r * 2 + 1];
            float4 o1, o2;
            o1.x = cp[0] + b1.x; o1.y = cp[1] + b1.y; o1.z = cp[2] + b1.z; o1.w = cp[3] + b1.w;
            o2.x = cp[4] + b2.x; o2.y = cp[5] + b2.y; o2.z = cp[6] + b2.z; o2.w = cp[7] + b2.w;
            o1.x = o1.x > 0.f ? o1.x : 0.f; o1.y = o1.y > 0.f ? o1.y : 0.f;
            o1.z = o1.z > 0.f ? o1.z : 0.f; o1.w = o1.w > 0.f ? o1.w : 0.f;
            o2.x = o2.x > 0.f ? o2.x : 0.f; o2.y = o2.y > 0.f ? o2.y : 0.f;
            o2.z = o2.z > 0.f ? o2.z : 0.f; o2.w = o2.w > 0.f ? o2.w : 0.f;
            float* op = out + (size_t)a * H + r * 8;
            *(float4*)op = o1;
            *(float4*)(op + 4) = o2;
        }
    }
}

// ---------------------------------------------------------------------------
extern "C" void kernel_launch(void* const* d_in, const int* in_sizes, int n_in,
                              void* d_out, int out_size, void* d_ws, size_t ws_size,
                              hipStream_t stream) {
    const float* fatoms = (const float*)d_in[0];
    const float* fbonds = (const float*)d_in[1];
    const int*   agraph = (const int*)d_in[2];
    const int*   bgraph = (const int*)d_in[3];
    const float* W_i    = (const float*)d_in[4];
    const float* W_h    = (const float*)d_in[5];
    const float* W_o    = (const float*)d_in[6];
    const float* b_o    = (const float*)d_in[7];
    float* out = (float*)d_out;

    const size_t MSG_BYTES = (size_t)N_BONDS * H * sizeof(ushort_t);   // 51.2 MB
    char* ws = (char*)d_ws;
    ushort_t* binput = (ushort_t*)(ws);
    ushort_t* msgA   = (ushort_t*)(ws + MSG_BYTES);
    ushort_t* msgB   = (ushort_t*)(ws + 2 * MSG_BYTES);
    ushort_t* pWi    = (ushort_t*)(ws + 3 * MSG_BYTES);                         // 16 KB
    ushort_t* pWh    = (ushort_t*)(ws + 3 * MSG_BYTES + 16 * 1024);             // 32 KB
    ushort_t* pWo    = (ushort_t*)(ws + 3 * MSG_BYTES + 48 * 1024);             // 48 KB

    k_pack<<<24, 256, 0, stream>>>(W_i, W_h, W_o, pWi, pWh, pWo);
    k_binput<<<N_BONDS / 64, 256, 0, stream>>>(fbonds, pWi, binput, msgA);

    ushort_t* cur = msgA;
    ushort_t* nxt = msgB;
    for (int d = 0; d < DEPTH - 1; ++d) {
        k_mp<<<N_BONDS / 64, 256, 0, stream>>>(cur, bgraph, pWh, binput, nxt);
        ushort_t* tmp = cur; cur = nxt; nxt = tmp;
    }

    k_out<<<(N_ATOMS + 63) / 64, 256, 0, stream>>>(cur, agraph, fatoms, pWo, b_o, out);
}

// Round 8
// 516.454 us; speedup vs baseline: 1.0541x; 1.0541x over previous
//
#include <hip/hip_runtime.h>

#define N_ATOMS   100000
#define N_BONDS   200000
#define MAX_NB    6
#define AF        39
#define BFEAT     50      // 39 + 11
#define H         128
#define DEPTH     6
#define KS_I      2       // k-steps (32 each) for the three GEMMs
#define KS_H      4
#define KS_O      6

typedef unsigned short ushort_t;
typedef unsigned int   uint_t;

typedef __attribute__((ext_vector_type(8))) short  bf16x8;
typedef __attribute__((ext_vector_type(4))) float  f32x4;

__device__ inline float bf2f(ushort_t u) {
    union { uint_t i; float f; } v; v.i = ((uint_t)u) << 16; return v.f;
}
__device__ inline ushort_t f2bf(float f) {
    union { float f; uint_t i; } v; v.f = f;
    uint_t x = v.i;
    uint_t r = (x + 0x7fffu + ((x >> 16) & 1u)) >> 16;   // RNE
    return (ushort_t)r;
}
__device__ inline uint_t pack2(float a, float b) {
    return (uint_t)f2bf(a) | ((uint_t)f2bf(b) << 16);
}
__device__ inline uint_t relu2(uint_t w) {
    uint_t lo = w & 0xffffu, hi = w >> 16;
    if (lo & 0x8000u) lo = 0;
    if (hi & 0x8000u) hi = 0;
    return lo | (hi << 16);
}
__device__ inline void addv(float* a, uint4 v) {
    a[0] += bf2f((ushort_t)(v.x & 0xffffu)); a[1] += bf2f((ushort_t)(v.x >> 16));
    a[2] += bf2f((ushort_t)(v.y & 0xffffu)); a[3] += bf2f((ushort_t)(v.y >> 16));
    a[4] += bf2f((ushort_t)(v.z & 0xffffu)); a[5] += bf2f((ushort_t)(v.z >> 16));
    a[6] += bf2f((ushort_t)(v.w & 0xffffu)); a[7] += bf2f((ushort_t)(v.w >> 16));
}
// relu-then-add: messages are stored PRE-relu; relu applied at gather time.
// relu(bf16(x)) == bf16(relu(x)) since RNE preserves sign -> bit-identical.
__device__ inline void addvr(float* a, uint4 v) {
    v.x = relu2(v.x); v.y = relu2(v.y); v.z = relu2(v.z); v.w = relu2(v.w);
    addv(a, v);
}

// ---------------------------------------------------------------------------
// Prep: pack W_i / W_h / W_o into MFMA B-fragment-major bf16 layout:
//   p[ks][nt][lane][j]  with  n = nt*16 + (lane&15),  k = ks*32 + (lane>>4)*8 + j
// ---------------------------------------------------------------------------
__global__ __launch_bounds__(256) void k_pack(const float* __restrict__ W_i,
                                              const float* __restrict__ W_h,
                                              const float* __restrict__ W_o,
                                              ushort_t* __restrict__ pWi,
                                              ushort_t* __restrict__ pWh,
                                              ushort_t* __restrict__ pWo) {
    int id = blockIdx.x * 256 + threadIdx.x;
    int mat;
    ushort_t* dst;
    if (id < 1024)        { mat = 0; dst = pWi; }
    else if (id < 3072)   { mat = 1; dst = pWh; id -= 1024; }
    else                  { mat = 2; dst = pWo; id -= 3072; }
    const int lane = id & 63;
    const int nt   = (id >> 6) & 7;
    const int ks   = id >> 9;
    const int n  = nt * 16 + (lane & 15);
    const int k0 = ks * 32 + (lane >> 4) * 8;
    float v[8];
#pragma unroll
    for (int j = 0; j < 8; ++j) {
        const int k = k0 + j;
        float x = 0.f;
        if (mat == 0)      { if (k < BFEAT) x = W_i[n * BFEAT + k]; }
        else if (mat == 1) { x = W_h[n * H + k]; }
        else {
            if (k < H)          x = W_o[(size_t)n * (AF + H) + AF + k];
            else if (k < H + AF) x = W_o[(size_t)n * (AF + H) + (k - H)];
        }
        v[j] = x;
    }
    uint4 u;
    u.x = pack2(v[0], v[1]); u.y = pack2(v[2], v[3]);
    u.z = pack2(v[4], v[5]); u.w = pack2(v[6], v[7]);
    ((uint4*)dst)[id] = u;
}

// ---------------------------------------------------------------------------
// Kernel 1: binput = fbonds @ W_i^T (bf16, PRE-relu). Writes binput ONLY;
// the first MP step gathers directly from binput applying relu on the fly.
// ---------------------------------------------------------------------------
__global__ __launch_bounds__(256) void k_binput(const float* __restrict__ fbonds,
                                                const ushort_t* __restrict__ pWi,
                                                ushort_t* __restrict__ binput) {
    __shared__ __align__(16) ushort_t sAC[64][136];   // 17408 B
    const int t = threadIdx.x;
    const int b0 = blockIdx.x * 64;

    // stage fbonds rows as bf16 via float2 (50 floats = 25 float2 per row)
    for (int i = t; i < 64 * 25; i += 256) {
        const int row = i / 25, j = i % 25;
        const float2 v = *(const float2*)(fbonds + (size_t)(b0 + row) * BFEAT + j * 2);
        *(uint_t*)&sAC[row][j * 2] = pack2(v.x, v.y);
    }
    // zero pad cols 50..63 (7 uints per row)
    for (int i = t; i < 64 * 7; i += 256) {
        const int row = i / 7, c = BFEAT + (i % 7) * 2;
        *(uint_t*)&sAC[row][c] = 0u;
    }
    __syncthreads();

    const int w    = t >> 6;
    const int lane = t & 63;
    const int col  = lane & 15;
    const int kg   = lane >> 4;
    const int m    = 16 * w + col;

    f32x4 acc[8];
#pragma unroll
    for (int nt = 0; nt < 8; ++nt) acc[nt] = (f32x4){0.f, 0.f, 0.f, 0.f};
    bf16x8 af[KS_I];
#pragma unroll
    for (int ks = 0; ks < KS_I; ++ks)
        af[ks] = *(const bf16x8*)&sAC[m][ks * 32 + kg * 8];
#pragma unroll
    for (int ks = 0; ks < KS_I; ++ks) {
#pragma unroll
        for (int nt = 0; nt < 8; ++nt) {
            const bf16x8 b = *(const bf16x8*)(pWi + (((size_t)(ks * 8 + nt) * 64 + lane) * 8));
            acc[nt] = __builtin_amdgcn_mfma_f32_16x16x32_bf16(af[ks], b, acc[nt], 0, 0, 0);
        }
    }
    // C -> own rows of sAC (per-wave slab; wave-order LDS ops, no barrier)
    const int row0 = kg * 4;
#pragma unroll
    for (int nt = 0; nt < 8; ++nt)
#pragma unroll
        for (int r = 0; r < 4; ++r)
            sAC[16 * w + row0 + r][nt * 16 + col] = f2bf(acc[nt][r]);
    __syncthreads();

    for (int i = t; i < 64 * 16; i += 256) {
        const int row = i >> 4, c0 = (i & 15) * 8;
        const uint4 v = *(const uint4*)&sAC[row][c0];
        *(uint4*)(binput + (size_t)(b0 + row) * H + c0) = v;
    }
}

// ---------------------------------------------------------------------------
// Fused MP step (R6 barrier structure): X_out[b] = binput[b] + relu-gather @ W_h^T
// Messages stored PRE-relu; gather applies relu2. Gather merged 2-passes for
// 12 in-flight uint4 loads; binput epilogue value prefetched before MFMA.
// LDS: sAC 17408 + sIdx 1536 -> 8 blocks/CU capacity.
// ---------------------------------------------------------------------------
__global__ __launch_bounds__(256) void k_mp(const ushort_t* __restrict__ msg_in,
                                            const int* __restrict__ bgraph,
                                            const ushort_t* __restrict__ pWh,
                                            const ushort_t* __restrict__ binput,
                                            ushort_t* __restrict__ msg_out) {
    __shared__ __align__(16) ushort_t sAC[64][136];   // gather-A, then bf16 C
    __shared__ int sIdx[64][MAX_NB];
    const int t = threadIdx.x;
    const int b0 = blockIdx.x * 64;

    for (int i = t; i < 64 * MAX_NB; i += 256)
        sIdx[i / MAX_NB][i % MAX_NB] = bgraph[(size_t)b0 * MAX_NB + i];
    __syncthreads();

    {   // gather-sum (relu applied) -> bf16 A tile. 2 merged passes:
        // per wave instruction: 4 rows x 256B contiguous segments.
        const int bi = t >> 4;          // 0..15
        const int c0 = (t & 15) * 8;    // col base
#pragma unroll
        for (int p = 0; p < 4; p += 2) {
            const int iA = p * 16 + bi;
            const int iB = iA + 16;
            uint4 vA[MAX_NB], vB[MAX_NB];
#pragma unroll
            for (int j = 0; j < MAX_NB; ++j)
                vA[j] = *(const uint4*)(msg_in + (size_t)sIdx[iA][j] * H + c0);
#pragma unroll
            for (int j = 0; j < MAX_NB; ++j)
                vB[j] = *(const uint4*)(msg_in + (size_t)sIdx[iB][j] * H + c0);
            float a[8], b[8];
#pragma unroll
            for (int q = 0; q < 8; ++q) { a[q] = 0.f; b[q] = 0.f; }
#pragma unroll
            for (int j = 0; j < MAX_NB; ++j) addvr(a, vA[j]);
#pragma unroll
            for (int j = 0; j < MAX_NB; ++j) addvr(b, vB[j]);
            uint4 ua, ub;
            ua.x = pack2(a[0], a[1]); ua.y = pack2(a[2], a[3]);
            ua.z = pack2(a[4], a[5]); ua.w = pack2(a[6], a[7]);
            ub.x = pack2(b[0], b[1]); ub.y = pack2(b[2], b[3]);
            ub.z = pack2(b[4], b[5]); ub.w = pack2(b[6], b[7]);
            *(uint4*)&sAC[iA][c0] = ua;
            *(uint4*)&sAC[iB][c0] = ub;
        }
    }
    __syncthreads();

    // prefetch epilogue binput values (HBM latency overlaps MFMA phase)
    uint4 biPF[4];
#pragma unroll
    for (int p = 0; p < 4; ++p) {
        const int i = t + p * 256;
        const int row = i >> 4, c0 = (i & 15) * 8;
        biPF[p] = *(const uint4*)(binput + (size_t)(b0 + row) * H + c0);
    }

    const int w    = t >> 6;
    const int lane = t & 63;
    const int col  = lane & 15;
    const int kg   = lane >> 4;
    const int m    = 16 * w + col;

    f32x4 acc[8];
#pragma unroll
    for (int nt = 0; nt < 8; ++nt) acc[nt] = (f32x4){0.f, 0.f, 0.f, 0.f};
    bf16x8 af[KS_H];
#pragma unroll
    for (int ks = 0; ks < KS_H; ++ks)
        af[ks] = *(const bf16x8*)&sAC[m][ks * 32 + kg * 8];
#pragma unroll
    for (int ks = 0; ks < KS_H; ++ks) {
#pragma unroll
        for (int nt = 0; nt < 8; ++nt) {
            const bf16x8 b = *(const bf16x8*)(pWh + (((size_t)(ks * 8 + nt) * 64 + lane) * 8));
            acc[nt] = __builtin_amdgcn_mfma_f32_16x16x32_bf16(af[ks], b, acc[nt], 0, 0, 0);
        }
    }
    // bf16 C into own rows of sAC (per-wave A region == C region)
    const int row0 = kg * 4;
#pragma unroll
    for (int nt = 0; nt < 8; ++nt)
#pragma unroll
        for (int r = 0; r < 4; ++r)
            sAC[16 * w + row0 + r][nt * 16 + col] = f2bf(acc[nt][r]);
    __syncthreads();

    // epilogue: X = binput + C  (NO relu; next gather applies it)
#pragma unroll
    for (int p = 0; p < 4; ++p) {
        const int i = t + p * 256;
        const int row = i >> 4, c0 = (i & 15) * 8;
        const size_t off = (size_t)(b0 + row) * H + c0;
        const uint4 bi4 = biPF[p];
        const uint4 cc  = *(const uint4*)&sAC[row][c0];
        uint4 o; float v0, v1;
        v0 = bf2f((ushort_t)(bi4.x & 0xffffu)) + bf2f((ushort_t)(cc.x & 0xffffu));
        v1 = bf2f((ushort_t)(bi4.x >> 16))     + bf2f((ushort_t)(cc.x >> 16));
        o.x = pack2(v0, v1);
        v0 = bf2f((ushort_t)(bi4.y & 0xffffu)) + bf2f((ushort_t)(cc.y & 0xffffu));
        v1 = bf2f((ushort_t)(bi4.y >> 16))     + bf2f((ushort_t)(cc.y >> 16));
        o.y = pack2(v0, v1);
        v0 = bf2f((ushort_t)(bi4.z & 0xffffu)) + bf2f((ushort_t)(cc.z & 0xffffu));
        v1 = bf2f((ushort_t)(bi4.z >> 16))     + bf2f((ushort_t)(cc.z >> 16));
        o.z = pack2(v0, v1);
        v0 = bf2f((ushort_t)(bi4.w & 0xffffu)) + bf2f((ushort_t)(cc.w & 0xffffu));
        v1 = bf2f((ushort_t)(bi4.w >> 16))     + bf2f((ushort_t)(cc.w >> 16));
        o.w = pack2(v0, v1);
        *(uint4*)(msg_out + off) = o;
    }
}

// ---------------------------------------------------------------------------
// Fused output: out = relu(b_o + [relu-gather(128) | fatoms(39) | 0] @ B^T)
// R6 barrier structure, fp32 C staging (union), relu2 at gather, merged passes.
// ---------------------------------------------------------------------------
__global__ __launch_bounds__(256) void k_out(const ushort_t* __restrict__ msg,
                                             const int* __restrict__ agraph,
                                             const float* __restrict__ fatoms,
                                             const ushort_t* __restrict__ pWo,
                                             const float* __restrict__ b_o,
                                             float* __restrict__ out) {
    __shared__ __align__(16) unsigned char smem[64 * 132 * 4];   // 33792 (sA 25600)
    ushort_t (*sA)[200] = (ushort_t(*)[200])smem;
    float    (*sC)[132] = (float(*)[132])smem;
    __shared__ int sIdx[64][MAX_NB];
    const int t = threadIdx.x;
    const int a0 = blockIdx.x * 64;

    for (int i = t; i < 64 * MAX_NB; i += 256) {
        const int a = a0 + i / MAX_NB;
        sIdx[i / MAX_NB][i % MAX_NB] = (a < N_ATOMS) ? agraph[(size_t)a * MAX_NB + (i % MAX_NB)] : 0;
    }
    for (int i = t; i < 64 * 64; i += 256) {
        const int row = i >> 6, c = i & 63;
        const int a = a0 + row;
        float x = 0.f;
        if (c < AF && a < N_ATOMS) x = fatoms[(size_t)a * AF + c];
        sA[row][H + c] = f2bf(x);
    }
    __syncthreads();

    {   // a_nei relu-gather -> cols 0..127, merged 2-passes
        const int bi = t >> 4;
        const int c0 = (t & 15) * 8;
#pragma unroll
        for (int p = 0; p < 4; p += 2) {
            const int iA = p * 16 + bi;
            const int iB = iA + 16;
            uint4 vA[MAX_NB], vB[MAX_NB];
#pragma unroll
            for (int j = 0; j < MAX_NB; ++j)
                vA[j] = *(const uint4*)(msg + (size_t)sIdx[iA][j] * H + c0);
#pragma unroll
            for (int j = 0; j < MAX_NB; ++j)
                vB[j] = *(const uint4*)(msg + (size_t)sIdx[iB][j] * H + c0);
            float a[8], b[8];
#pragma unroll
            for (int q = 0; q < 8; ++q) { a[q] = 0.f; b[q] = 0.f; }
#pragma unroll
            for (int j = 0; j < MAX_NB; ++j) addvr(a, vA[j]);
#pragma unroll
            for (int j = 0; j < MAX_NB; ++j) addvr(b, vB[j]);
            uint4 ua, ub;
            ua.x = pack2(a[0], a[1]); ua.y = pack2(a[2], a[3]);
            ua.z = pack2(a[4], a[5]); ua.w = pack2(a[6], a[7]);
            ub.x = pack2(b[0], b[1]); ub.y = pack2(b[2], b[3]);
            ub.z = pack2(b[4], b[5]); ub.w = pack2(b[6], b[7]);
            *(uint4*)&sA[iA][c0] = ua;
            *(uint4*)&sA[iB][c0] = ub;
        }
    }
    __syncthreads();

    const int w    = t >> 6;
    const int lane = t & 63;
    const int col  = lane & 15;
    const int kg   = lane >> 4;
    const int m    = 16 * w + col;

    f32x4 acc[8];
#pragma unroll
    for (int nt = 0; nt < 8; ++nt) acc[nt] = (f32x4){0.f, 0.f, 0.f, 0.f};
#pragma unroll
    for (int ks = 0; ks < KS_O; ++ks) {
        const bf16x8 a = *(const bf16x8*)&sA[m][ks * 32 + kg * 8];
#pragma unroll
        for (int nt = 0; nt < 8; ++nt) {
            const bf16x8 b = *(const bf16x8*)(pWo + (((size_t)(ks * 8 + nt) * 64 + lane) * 8));
            acc[nt] = __builtin_amdgcn_mfma_f32_16x16x32_bf16(a, b, acc[nt], 0, 0, 0);
        }
    }
    __syncthreads();

    const int row0 = kg * 4;
#pragma unroll
    for (int nt = 0; nt < 8; ++nt)
#pragma unroll
        for (int r = 0; r < 4; ++r)
            sC[16 * w + row0 + r][nt * 16 + col] = acc[nt][r];
    __syncthreads();

    const float4* bo4 = (const float4*)b_o;
    for (int i = t; i < 64 * 16; i += 256) {
        const int row = i >> 4, c0 = (i & 15) * 8;
        const int a = a0 + row;
        if (a < N_ATOMS) {
            const float* cp = &sC[row][c0];
            const float4 b1 = bo4[c0 >> 2];
            const float4 b2 = bo4[(c0 >> 2) + 1];
            float4 o1, o2;
            o1.x = cp[0] + b1.x; o1.y = cp[1] + b1.y; o1.z = cp[2] + b1.z; o1.w = cp[3] + b1.w;
            o2.x = cp[4] + b2.x; o2.y = cp[5] + b2.y; o2.z = cp[6] + b2.z; o2.w = cp[7] + b2.w;
            o1.x = o1.x > 0.f ? o1.x : 0.f; o1.y = o1.y > 0.f ? o1.y : 0.f;
            o1.z = o1.z > 0.f ? o1.z : 0.f; o1.w = o1.w > 0.f ? o1.w : 0.f;
            o2.x = o2.x > 0.f ? o2.x : 0.f; o2.y = o2.y > 0.f ? o2.y : 0.f;
            o2.z = o2.z > 0.f ? o2.z : 0.f; o2.w = o2.w > 0.f ? o2.w : 0.f;
            float* op = out + (size_t)a * H + c0;
            *(float4*)op = o1;
            *(float4*)(op + 4) = o2;
        }
    }
}

// ---------------------------------------------------------------------------
extern "C" void kernel_launch(void* const* d_in, const int* in_sizes, int n_in,
                              void* d_out, int out_size, void* d_ws, size_t ws_size,
                              hipStream_t stream) {
    const float* fatoms = (const float*)d_in[0];
    const float* fbonds = (const float*)d_in[1];
    const int*   agraph = (const int*)d_in[2];
    const int*   bgraph = (const int*)d_in[3];
    const float* W_i    = (const float*)d_in[4];
    const float* W_h    = (const float*)d_in[5];
    const float* W_o    = (const float*)d_in[6];
    const float* b_o    = (const float*)d_in[7];
    float* out = (float*)d_out;

    const size_t MSG_BYTES = (size_t)N_BONDS * H * sizeof(ushort_t);   // 51.2 MB
    char* ws = (char*)d_ws;
    ushort_t* binput = (ushort_t*)(ws);
    ushort_t* msgA   = (ushort_t*)(ws + MSG_BYTES);
    ushort_t* msgB   = (ushort_t*)(ws + 2 * MSG_BYTES);
    ushort_t* pWi    = (ushort_t*)(ws + 3 * MSG_BYTES);                         // 16 KB
    ushort_t* pWh    = (ushort_t*)(ws + 3 * MSG_BYTES + 16 * 1024);             // 32 KB
    ushort_t* pWo    = (ushort_t*)(ws + 3 * MSG_BYTES + 48 * 1024);             // 48 KB

    k_pack<<<24, 256, 0, stream>>>(W_i, W_h, W_o, pWi, pWh, pWo);
    k_binput<<<N_BONDS / 64, 256, 0, stream>>>(fbonds, pWi, binput);

    // messages stored PRE-relu; X_0 == binput, so first step gathers from it.
    ushort_t* bufs[2] = { msgA, msgB };
    const ushort_t* cur = binput;
    for (int d = 0; d < DEPTH - 1; ++d) {
        ushort_t* nxt = bufs[d & 1];
        k_mp<<<N_BONDS / 64, 256, 0, stream>>>(cur, bgraph, pWh, binput, nxt);
        cur = nxt;
    }

    k_out<<<(N_ATOMS + 63) / 64, 256, 0, stream>>>(cur, agraph, fatoms, pWo, b_o, out);
}